// Round 7
// baseline (1265.626 us; speedup 1.0000x reference)
//
#include <hip/hip_runtime.h>

// Problem constants (from reference)
constexpr int BATCH = 16384;
constexpr int NN    = 4096;    // NUM_NEURONS
constexpr int BS    = 32;      // BLOCK_SIZE
constexpr int NB    = NN / BS; // 128 blocks

constexpr int THREADS     = 256;   // 4 waves
constexpr int ROWS_PER_WG = 512;
constexpr int ROWS_PER_IT = 64;    // 4 waves x 16 rows
constexpr int ITERS       = ROWS_PER_WG / ROWS_PER_IT; // 8

typedef float f32x4 __attribute__((ext_vector_type(4)));
typedef float f32x2 __attribute__((ext_vector_type(2)));

// Lane layout: r = lane>>2 (row, 16 rows/wave), q = lane&3. Each lane owns
// 8 output columns {4q..4q+3, 16+4q..16+4q+3} and holds the matching v
// elements w[0]=v[row,4q..4q+3], w[1]=v[row,16+4q..16+4q+3].
//
// v[row,k] broadcast: owner of k is lane (k>>2)&3 within the quad ->
// quad_perm DPP broadcast on the VALU pipe, zero DS-pipe traffic.
// Per k-step: 2 conflict-free ds_read_b128 of A[k] + 8 FMAs.

template <int S>
__device__ __forceinline__ float qbcast(float x) {
    return __int_as_float(__builtin_amdgcn_update_dpp(
        0, __float_as_int(x), S * 0x55, 0xF, 0xF, true));
}

template <int K>
struct KStep {
    static __device__ __forceinline__ void run(const f32x4* __restrict__ w,
                                               const float* __restrict__ Alds,
                                               int q, float* __restrict__ acc) {
        constexpr int s = (K >> 2) & 3;  // owner lane within quad
        constexpr int h = K >> 4;        // which w register
        constexpr int e = K & 3;         // component
        const float vk = qbcast<s>(w[h][e]);
        const f32x4 a0 = *reinterpret_cast<const f32x4*>(Alds + K * BS + q * 4);
        const f32x4 a1 = *reinterpret_cast<const f32x4*>(Alds + K * BS + q * 4 + 16);
        acc[0] = fmaf(vk, a0.x, acc[0]);
        acc[1] = fmaf(vk, a0.y, acc[1]);
        acc[2] = fmaf(vk, a0.z, acc[2]);
        acc[3] = fmaf(vk, a0.w, acc[3]);
        acc[4] = fmaf(vk, a1.x, acc[4]);
        acc[5] = fmaf(vk, a1.y, acc[5]);
        acc[6] = fmaf(vk, a1.z, acc[6]);
        acc[7] = fmaf(vk, a1.w, acc[7]);
        KStep<K + 1>::run(w, Alds, q, acc);
    }
};
template <>
struct KStep<BS> {
    static __device__ __forceinline__ void run(const f32x4* __restrict__,
                                               const float* __restrict__,
                                               int, float* __restrict__) {}
};

// Cap VGPR at 128 (4 waves/SIMD). Live set ~90 VGPR -> safe slack; this
// mainly stops the scheduler from hoisting all 64 ds_read destinations
// (R6: VGPR=160, 3 waves/SIMD).
__global__ __launch_bounds__(THREADS, 4) void tn_kernel(
    const float* __restrict__ v,
    const float* __restrict__ dx,
    const float* __restrict__ A,
    const float* __restrict__ Bm,
    const float* __restrict__ bsc,
    float* __restrict__ out)
{
    __shared__ float Alds[BS * BS]; // A[k][l], l fastest

    const int tid  = threadIdx.x;
    const int nblk = blockIdx.x & (NB - 1);
    const int rt   = blockIdx.x >> 7;

    reinterpret_cast<f32x4*>(Alds)[tid] =
        reinterpret_cast<const f32x4*>(A + nblk * (BS * BS))[tid];
    __syncthreads();

    const float bias = *bsc;
    const int lane = tid & 63;
    const int wv   = tid >> 6;
    const int r    = lane >> 2;
    const int q    = lane & 3;

    const float* Bb = Bm + nblk * (BS * 2);
    const f32x4 B0a = *reinterpret_cast<const f32x4*>(Bb + q * 8);
    const f32x4 B0b = *reinterpret_cast<const f32x4*>(Bb + q * 8 + 4);
    const f32x4 B1a = *reinterpret_cast<const f32x4*>(Bb + 32 + q * 8);
    const f32x4 B1b = *reinterpret_cast<const f32x4*>(Bb + 32 + q * 8 + 4);

    const int row0 = rt * ROWS_PER_WG + wv * 16 + r;
    const size_t rb0 = (size_t)row0 * NN + nblk * BS;
    constexpr size_t IT_STRIDE = (size_t)ROWS_PER_IT * NN;

    // 2-deep software pipeline: named buffers, static indexing only.
    f32x4 w0a, w0b, w1a, w1b, w2a, w2b;
    f32x2 d0, d1, d2;

    w0a = *reinterpret_cast<const f32x4*>(v + rb0 + q * 4);
    w0b = *reinterpret_cast<const f32x4*>(v + rb0 + q * 4 + 16);
    d0  = *reinterpret_cast<const f32x2*>(dx + (size_t)row0 * 2);
    w1a = *reinterpret_cast<const f32x4*>(v + rb0 + IT_STRIDE + q * 4);
    w1b = *reinterpret_cast<const f32x4*>(v + rb0 + IT_STRIDE + q * 4 + 16);
    d1  = *reinterpret_cast<const f32x2*>(dx + (size_t)(row0 + ROWS_PER_IT) * 2);

#pragma unroll 1
    for (int it = 0; it < ITERS; ++it) {
        if (it < ITERS - 2) {
            const size_t rbn = rb0 + (size_t)(it + 2) * IT_STRIDE;
            w2a = *reinterpret_cast<const f32x4*>(v + rbn + q * 4);
            w2b = *reinterpret_cast<const f32x4*>(v + rbn + q * 4 + 16);
            d2  = *reinterpret_cast<const f32x2*>(
                      dx + (size_t)(row0 + (it + 2) * ROWS_PER_IT) * 2);
        } else {
            w2a = w0a; w2b = w0b; d2 = d0;   // dummy, keeps regs live
        }

        f32x4 wcur[2] = {w0a, w0b};
        float acc[8] = {};
        KStep<0>::run(wcur, Alds, q, acc);

        f32x4 o0, o1;
        o0.x = fmaxf(fmaf(d0.x, B0a.x, fmaf(d0.y, B0a.y, acc[0] + bias)), 0.f);
        o0.y = fmaxf(fmaf(d0.x, B0a.z, fmaf(d0.y, B0a.w, acc[1] + bias)), 0.f);
        o0.z = fmaxf(fmaf(d0.x, B0b.x, fmaf(d0.y, B0b.y, acc[2] + bias)), 0.f);
        o0.w = fmaxf(fmaf(d0.x, B0b.z, fmaf(d0.y, B0b.w, acc[3] + bias)), 0.f);
        o1.x = fmaxf(fmaf(d0.x, B1a.x, fmaf(d0.y, B1a.y, acc[4] + bias)), 0.f);
        o1.y = fmaxf(fmaf(d0.x, B1a.z, fmaf(d0.y, B1a.w, acc[5] + bias)), 0.f);
        o1.z = fmaxf(fmaf(d0.x, B1b.x, fmaf(d0.y, B1b.y, acc[6] + bias)), 0.f);
        o1.w = fmaxf(fmaf(d0.x, B1b.z, fmaf(d0.y, B1b.w, acc[7] + bias)), 0.f);

        const size_t rbw = rb0 + (size_t)it * IT_STRIDE;
        __builtin_nontemporal_store(o0, reinterpret_cast<f32x4*>(out + rbw + q * 4));
        __builtin_nontemporal_store(o1, reinterpret_cast<f32x4*>(out + rbw + q * 4 + 16));

        // rotate pipeline
        w0a = w1a; w0b = w1b; d0 = d1;
        w1a = w2a; w1b = w2b; d1 = d2;
    }
}

extern "C" void kernel_launch(void* const* d_in, const int* in_sizes, int n_in,
                              void* d_out, int out_size, void* d_ws, size_t ws_size,
                              hipStream_t stream) {
    const float* v  = (const float*)d_in[0];  // [16384,4096]
    const float* dx = (const float*)d_in[1];  // [16384,2]
    const float* A  = (const float*)d_in[2];  // [128,32,32]
    const float* Bm = (const float*)d_in[3];  // [4096,2]
    const float* b  = (const float*)d_in[4];  // scalar
    float* out = (float*)d_out;               // [16384,4096]

    const int grid = NB * (BATCH / ROWS_PER_WG); // 128 * 32 = 4096
    tn_kernel<<<dim3(grid), dim3(THREADS), 0, stream>>>(v, dx, A, Bm, b, out);
}